// Round 1
// baseline (114.441 us; speedup 1.0000x reference)
//
#include <hip/hip_runtime.h>

#define HDIM 768
#define EDIM 128
#define BDIM 64

// Kernel 1: S-partials. core is [E,E,E] row-major; S[i] = sum of the
// contiguous 16384-float slab core[i,:,:]. 8 blocks per i, each block
// reduces a 2048-float chunk (256 threads x 2 float4) -> partials[i*8+chunk].
__global__ __launch_bounds__(256) void core_reduce_kernel(
    const float* __restrict__ core, float* __restrict__ partials) {
    const int gid   = blockIdx.x;      // 0..1023
    const int i     = gid >> 3;        // 0..127
    const int chunk = gid & 7;         // 0..7
    const float4* p = (const float4*)(core + (size_t)i * 16384 + (size_t)chunk * 2048);
    const int t = threadIdx.x;

    float4 a = p[t];
    float4 b = p[t + 256];
    float s = (a.x + a.y) + (a.z + a.w) + (b.x + b.y) + (b.z + b.w);

    // wave64 shuffle reduction
    for (int off = 32; off; off >>= 1) s += __shfl_down(s, off, 64);

    __shared__ float wpart[4];
    const int wave = t >> 6, lane = t & 63;
    if (lane == 0) wpart[wave] = s;
    __syncthreads();
    if (t == 0) partials[gid] = (wpart[0] + wpart[1]) + (wpart[2] + wpart[3]);
}

// Kernel 2: one block per batch element b; thread i in [0,128) owns output
// channel i. energy[b] = -sum_i S[i] * head[b,i] * rel[b,i] * tail[b,i].
__global__ __launch_bounds__(128) void energy_kernel(
    const float* __restrict__ head_src, const float* __restrict__ rel_src,
    const float* __restrict__ tail_src, const float* __restrict__ W_e,
    const float* __restrict__ b_e, const float* __restrict__ W_r,
    const float* __restrict__ b_r, const float* __restrict__ partials,
    float* __restrict__ out) {
    const int b = blockIdx.x;
    const int i = threadIdx.x;  // 0..127

    __shared__ float s_h[HDIM], s_r[HDIM], s_t[HDIM];
    for (int k = i; k < HDIM; k += 128) {
        s_h[k] = head_src[b * HDIM + k];
        s_r[k] = rel_src[b * HDIM + k];
        s_t[k] = tail_src[b * HDIM + k];
    }
    __syncthreads();

    float S = 0.f;
#pragma unroll
    for (int c = 0; c < 8; ++c) S += partials[i * 8 + c];

    const float4* we  = (const float4*)(W_e + i * HDIM);
    const float4* wr  = (const float4*)(W_r + i * HDIM);
    const float4* sh4 = (const float4*)s_h;
    const float4* sr4 = (const float4*)s_r;
    const float4* st4 = (const float4*)s_t;

    float h = 0.f, r = 0.f, tt = 0.f;
#pragma unroll 4
    for (int k = 0; k < HDIM / 4; ++k) {
        float4 w0 = we[k], w1 = wr[k];
        float4 hv = sh4[k], rv = sr4[k], tv = st4[k];
        h  += w0.x * hv.x + w0.y * hv.y + w0.z * hv.z + w0.w * hv.w;
        tt += w0.x * tv.x + w0.y * tv.y + w0.z * tv.z + w0.w * tv.w;
        r  += w1.x * rv.x + w1.y * rv.y + w1.z * rv.z + w1.w * rv.w;
    }
    h  += b_e[i];
    tt += b_e[i];
    r  += b_r[i];

    float val = S * h * r * tt;

    // reduce 128 values across 2 waves
    for (int off = 32; off; off >>= 1) val += __shfl_down(val, off, 64);
    __shared__ float wsum[2];
    if ((i & 63) == 0) wsum[i >> 6] = val;
    __syncthreads();
    if (i == 0) out[b] = -(wsum[0] + wsum[1]);
}

extern "C" void kernel_launch(void* const* d_in, const int* in_sizes, int n_in,
                              void* d_out, int out_size, void* d_ws, size_t ws_size,
                              hipStream_t stream) {
    const float* head_src = (const float*)d_in[0];
    const float* rel_src  = (const float*)d_in[1];
    const float* tail_src = (const float*)d_in[2];
    const float* W_e      = (const float*)d_in[3];
    const float* b_e      = (const float*)d_in[4];
    const float* W_r      = (const float*)d_in[5];
    const float* b_r      = (const float*)d_in[6];
    const float* core     = (const float*)d_in[7];
    float* out      = (float*)d_out;
    float* partials = (float*)d_ws;  // 1024 floats = 4 KB

    core_reduce_kernel<<<1024, 256, 0, stream>>>(core, partials);
    energy_kernel<<<BDIM, 128, 0, stream>>>(head_src, rel_src, tail_src,
                                            W_e, b_e, W_r, b_r, partials, out);
}

// Round 2
// 79.479 us; speedup vs baseline: 1.4399x; 1.4399x over previous
//
#include <hip/hip_runtime.h>

#define HDIM 768
#define EDIM 128
#define BDIM 64

#define NCORE_BLOCKS 1024
#define NPROJ_BLOCKS 768   // 3072 waves: (3 matrices x 64 b x 16 i-chunks)

// Fused kernel.
// Blocks [0,1024): reduce core[i,:,:] chunks -> partials[1024] (8 per i).
// Blocks [1024,1792): projections. Each wave computes 8 output channels of
// one (matrix m, batch b): coalesced float4 loads of src row (held in regs)
// and W rows, 12 FMAs + 6-shuffle wave reduce per channel.
__global__ __launch_bounds__(256) void fused_kernel(
    const float* __restrict__ core,
    const float* __restrict__ head_src, const float* __restrict__ rel_src,
    const float* __restrict__ tail_src,
    const float* __restrict__ W_e, const float* __restrict__ b_e,
    const float* __restrict__ W_r, const float* __restrict__ b_r,
    float* __restrict__ partials, float* __restrict__ P) {
    __shared__ float wpart[4];
    const int blk = blockIdx.x;
    const int t = threadIdx.x;
    const int wave = t >> 6, lane = t & 63;

    if (blk < NCORE_BLOCKS) {
        const int i     = blk >> 3;
        const int chunk = blk & 7;
        const float4* p = (const float4*)(core + (size_t)i * 16384 + (size_t)chunk * 2048);
        float4 a = p[t];
        float4 b = p[t + 256];
        float s = (a.x + a.y) + (a.z + a.w) + (b.x + b.y) + (b.z + b.w);
        for (int off = 32; off; off >>= 1) s += __shfl_down(s, off, 64);
        if (lane == 0) wpart[wave] = s;
        __syncthreads();
        if (t == 0) partials[blk] = (wpart[0] + wpart[1]) + (wpart[2] + wpart[3]);
    } else {
        const int pid = blk - NCORE_BLOCKS;
        const int wg  = pid * 4 + wave;     // 0..3071
        const int ich = wg & 15;            // i-chunk 0..15
        const int mb  = wg >> 4;            // 0..191
        const int m   = mb >> 6;            // 0=head 1=rel 2=tail
        const int b   = mb & 63;

        const float* src  = (m == 0) ? head_src : (m == 1) ? rel_src : tail_src;
        const float* W    = (m == 1) ? W_r : W_e;
        const float* bias = (m == 1) ? b_r : b_e;

        // src row fragment in registers: lane covers cols {lane*4, 256+lane*4, 512+lane*4}
        const float4* s4 = (const float4*)(src + b * HDIM);
        const float4 x0 = s4[lane], x1 = s4[lane + 64], x2 = s4[lane + 128];

        const int i0 = ich * 8;
#pragma unroll
        for (int u = 0; u < 8; ++u) {
            const int i = i0 + u;
            const float4* w4 = (const float4*)(W + i * HDIM);
            const float4 w0 = w4[lane], w1 = w4[lane + 64], w2 = w4[lane + 128];
            float d = w0.x * x0.x + w0.y * x0.y + w0.z * x0.z + w0.w * x0.w
                    + w1.x * x1.x + w1.y * x1.y + w1.z * x1.z + w1.w * x1.w
                    + w2.x * x2.x + w2.y * x2.y + w2.z * x2.z + w2.w * x2.w;
            for (int off = 32; off; off >>= 1) d += __shfl_down(d, off, 64);
            if (lane == 0) P[(m * BDIM + b) * EDIM + i] = d + bias[i];
        }
    }
}

// Final: one block per b. thread i: val = S[i]*h*r*t; block-reduce -> out[b].
__global__ __launch_bounds__(128) void final_kernel(
    const float* __restrict__ partials, const float* __restrict__ P,
    float* __restrict__ out) {
    const int b = blockIdx.x;
    const int i = threadIdx.x;  // 0..127

    float S = 0.f;
#pragma unroll
    for (int c = 0; c < 8; ++c) S += partials[i * 8 + c];

    const float h = P[(0 * BDIM + b) * EDIM + i];
    const float r = P[(1 * BDIM + b) * EDIM + i];
    const float tt = P[(2 * BDIM + b) * EDIM + i];
    float val = S * h * r * tt;

    for (int off = 32; off; off >>= 1) val += __shfl_down(val, off, 64);
    __shared__ float wsum[2];
    if ((i & 63) == 0) wsum[i >> 6] = val;
    __syncthreads();
    if (i == 0) out[b] = -(wsum[0] + wsum[1]);
}

extern "C" void kernel_launch(void* const* d_in, const int* in_sizes, int n_in,
                              void* d_out, int out_size, void* d_ws, size_t ws_size,
                              hipStream_t stream) {
    const float* head_src = (const float*)d_in[0];
    const float* rel_src  = (const float*)d_in[1];
    const float* tail_src = (const float*)d_in[2];
    const float* W_e      = (const float*)d_in[3];
    const float* b_e      = (const float*)d_in[4];
    const float* W_r      = (const float*)d_in[5];
    const float* b_r      = (const float*)d_in[6];
    const float* core     = (const float*)d_in[7];
    float* out      = (float*)d_out;
    float* partials = (float*)d_ws;                 // 1024 floats
    float* P        = (float*)d_ws + NCORE_BLOCKS;  // 3*64*128 = 24576 floats

    fused_kernel<<<NCORE_BLOCKS + NPROJ_BLOCKS, 256, 0, stream>>>(
        core, head_src, rel_src, tail_src, W_e, b_e, W_r, b_r, partials, P);
    final_kernel<<<BDIM, 128, 0, stream>>>(partials, P, out);
}